// Round 8
// baseline (105.315 us; speedup 1.0000x reference)
//
#include <hip/hip_runtime.h>

#define N_NODES 50000
#define N_EDGES 800000
#define SCAN_NB 49        // ceil(50000 / 1024) blocks, 1024 elements per block

#define NBUCKETS 196      // ceil(50000/256): bucket = dst >> 8 (256 nodes each)
#define BIN_EDGES 4096    // edges per bin block
#define BIN_NB 196        // ceil(800000/4096)
#define BUCKET_CAP 5120   // slots per bucket (mean 4096, sd ~64 -> 16 sigma margin)

#define GEMM_NB ((N_NODES + 31) / 32)          // 1563 gemm tiles
#define FUSED_NB (BIN_NB * 9)                  // 1764: bid%9==8 -> bin role

typedef __attribute__((ext_vector_type(4))) _Float16 half4;
typedef __attribute__((ext_vector_type(8))) _Float16 half8;

// Recover in-degree from GCN norm: norm = max(deg,1)^-0.5 (fp32).
// deg=0 reconstructs as 1 (harmless over-allocation; aggregate uses the
// post-scatter cursor as end pointer, so phantom slots are never read).
__device__ __forceinline__ int deg_from_norm(float n)
{
    return __float2int_rn(1.0f / (n * n));
}

// -------- Fused Kernel A: pipelined gemm_scale tiles + edge binning -------
// Blocks with bid%9==8 bin 4096 edges into per-bucket sequential streams
// (bucket = dst>>8); the rest compute one 32-row GEMM tile each.
// GEMM pipelining (round 8): full H tile staged up-front (4 float4/thread in
// flight -> one HBM latency instead of four), W chunks double-buffered with
// register prefetch issued before each compute phase (L2-resident, hidden).
// One barrier per chunk. Buffer reuse at chunk i+2 is safe: the barrier at
// chunk i (placed after every wave's ds_write of chunk i+1, hence after its
// compute of chunk i) guarantees no wave still reads the buffer being
// overwritten.
// SESSION RULE (rounds 2 & 4): no min-waves clause — it collapses VGPRs and
// spills the accumulators (WRITE_SIZE tripwire 12.5 MB -> 183-564 MB).
__global__ __launch_bounds__(256) void fused_gemm_bin_kernel(
    const float* __restrict__ h, const float* __restrict__ norm,
    const float* __restrict__ W, _Float16* __restrict__ t,
    const int* __restrict__ src, const int* __restrict__ dst,
    int* __restrict__ bcur, int2* __restrict__ bucketbuf)
{
    const int tid = threadIdx.x;
    const int bid = blockIdx.x;

    if (bid % 9 == 8) {
        // ---- bin role: 4096 edges -> 196 bucket streams --------------------
        __shared__ int hist[NBUCKETS];
        const int bs = (bid / 9) * BIN_EDGES;
        for (int i = tid; i < NBUCKETS; i += 256) hist[i] = 0;
        __syncthreads();
#pragma unroll
        for (int j = 0; j < 4; ++j) {
            int e4 = bs + (j * 256 + tid) * 4;
            if (e4 < N_EDGES) {               // 4096 & 1280 both %4==0
                int4 d4 = *(const int4*)(dst + e4);
                atomicAdd(&hist[d4.x >> 8], 1);
                atomicAdd(&hist[d4.y >> 8], 1);
                atomicAdd(&hist[d4.z >> 8], 1);
                atomicAdd(&hist[d4.w >> 8], 1);
            }
        }
        __syncthreads();
        int base = 0;
        if (tid < NBUCKETS) {
            int hc = hist[tid];
            if (hc) base = atomicAdd(&bcur[tid], hc);
        }
        __syncthreads();
        if (tid < NBUCKETS) hist[tid] = base;   // reuse as running cursor
        __syncthreads();
#pragma unroll
        for (int j = 0; j < 4; ++j) {
            int e4 = bs + (j * 256 + tid) * 4;
            if (e4 < N_EDGES) {
                int4 d4 = *(const int4*)(dst + e4);
                int4 s4 = *(const int4*)(src + e4);
                int b0, p;
                b0 = d4.x >> 8; p = atomicAdd(&hist[b0], 1);
                bucketbuf[(size_t)b0 * BUCKET_CAP + p] = make_int2(s4.x, d4.x);
                b0 = d4.y >> 8; p = atomicAdd(&hist[b0], 1);
                bucketbuf[(size_t)b0 * BUCKET_CAP + p] = make_int2(s4.y, d4.y);
                b0 = d4.z >> 8; p = atomicAdd(&hist[b0], 1);
                bucketbuf[(size_t)b0 * BUCKET_CAP + p] = make_int2(s4.z, d4.z);
                b0 = d4.w >> 8; p = atomicAdd(&hist[b0], 1);
                bucketbuf[(size_t)b0 * BUCKET_CAP + p] = make_int2(s4.w, d4.w);
            }
        }
        return;
    }

    // ---- gemm role: one 32-row tile, pipelined -----------------------------
    __shared__ float Ws[2][32 * 128];  // double-buffered W chunk, 2 x 16 KB
    __shared__ float Hs[32 * 132];     // full-depth H tile, stride 132, 16.9 KB
    const int gemm_id = bid - bid / 9;
    if (gemm_id >= GEMM_NB) return;
    const int rbase = gemm_id * 32;

    const int rt = tid >> 5, ct = tid & 31;
    const int r0 = rt * 4, c0 = ct * 4;

    // issue ALL H loads (4 float4/thread, 4 outstanding HBM reqs) + W chunk 0
    float4 hreg[4];
#pragma unroll
    for (int i = 0; i < 4; ++i) {
        int f = i * 256 + tid;            // 0..1023
        int row = f >> 5;                 // 0..31
        int c = (f & 31) << 2;            // 0..124
        int gr = rbase + row;
        hreg[i] = make_float4(0.f, 0.f, 0.f, 0.f);
        if (gr < N_NODES) hreg[i] = *(const float4*)(h + (size_t)gr * 128 + c);
    }
    const float4* Wg4 = (const float4*)W;
    float4 wreg[4];
#pragma unroll
    for (int i = 0; i < 4; ++i) wreg[i] = Wg4[i * 256 + tid];

#pragma unroll
    for (int i = 0; i < 4; ++i) {
        int f = i * 256 + tid;
        int row = f >> 5;
        int c = (f & 31) << 2;
        *(float4*)(Hs + row * 132 + c) = hreg[i];
    }
    {
        float4* Wd = (float4*)Ws[0];
#pragma unroll
        for (int i = 0; i < 4; ++i) Wd[i * 256 + tid] = wreg[i];
    }
    __syncthreads();

    float acc[4][4];
#pragma unroll
    for (int i = 0; i < 4; ++i)
#pragma unroll
        for (int j = 0; j < 4; ++j) acc[i][j] = 0.f;

    int buf = 0;
    for (int kcId = 0; kcId < 4; ++kcId) {
        // prefetch next W chunk to registers (L2-resident, hides under compute)
        if (kcId < 3) {
#pragma unroll
            for (int i = 0; i < 4; ++i)
                wreg[i] = Wg4[(kcId + 1) * 1024 + i * 256 + tid];
        }
        const float* Wb = Ws[buf];
        const int kb = kcId * 32;
#pragma unroll
        for (int k = 0; k < 32; k += 4) {
            float4 w0 = *(const float4*)(Wb + (k + 0) * 128 + c0);
            float4 w1 = *(const float4*)(Wb + (k + 1) * 128 + c0);
            float4 w2 = *(const float4*)(Wb + (k + 2) * 128 + c0);
            float4 w3 = *(const float4*)(Wb + (k + 3) * 128 + c0);
#pragma unroll
            for (int i = 0; i < 4; ++i) {
                float4 hv = *(const float4*)(Hs + (r0 + i) * 132 + kb + k);
                acc[i][0] += hv.x * w0.x + hv.y * w1.x + hv.z * w2.x + hv.w * w3.x;
                acc[i][1] += hv.x * w0.y + hv.y * w1.y + hv.z * w2.y + hv.w * w3.y;
                acc[i][2] += hv.x * w0.z + hv.y * w1.z + hv.z * w2.z + hv.w * w3.z;
                acc[i][3] += hv.x * w0.w + hv.y * w1.w + hv.z * w2.w + hv.w * w3.w;
            }
        }
        if (kcId < 3) {
            float4* Wd = (float4*)Ws[buf ^ 1];
#pragma unroll
            for (int i = 0; i < 4; ++i) Wd[i * 256 + tid] = wreg[i];
            __syncthreads();
            buf ^= 1;
        }
    }

#pragma unroll
    for (int i = 0; i < 4; ++i) {
        int gr = rbase + r0 + i;
        if (gr < N_NODES) {
            float nv = norm[gr];
            half4 v;
            v.x = (_Float16)(acc[i][0] * nv);
            v.y = (_Float16)(acc[i][1] * nv);
            v.z = (_Float16)(acc[i][2] * nv);
            v.w = (_Float16)(acc[i][3] * nv);
            *(half4*)(t + (size_t)gr * 128 + c0) = v;
        }
    }
}

// -------- CSR build step 1: per-block degree sums (from norm) -------------
// Block 0 also zeroes the 196 bucket cursors for the binning pass.
__global__ __launch_bounds__(256) void scan_sums_kernel(
    const float* __restrict__ norm, int* __restrict__ bsum,
    int* __restrict__ bcur)
{
    const int tid = threadIdx.x;
    if (blockIdx.x == 0 && tid < NBUCKETS) bcur[tid] = 0;
    const int idx = blockIdx.x * 1024 + tid * 4;
    int s = 0;
    if (idx < N_NODES) {                 // 50000 % 4 == 0: group fully in-range
        float4 n = *(const float4*)(norm + idx);
        s = deg_from_norm(n.x) + deg_from_norm(n.y) +
            deg_from_norm(n.z) + deg_from_norm(n.w);
    }
#pragma unroll
    for (int d = 32; d > 0; d >>= 1) s += __shfl_down(s, d);
    __shared__ int ws[4];
    if ((tid & 63) == 0) ws[tid >> 6] = s;
    __syncthreads();
    if (tid == 0) bsum[blockIdx.x] = ws[0] + ws[1] + ws[2] + ws[3];
}

// -------- CSR build step 2: exclusive scan of 49 block sums (1 wave) ------
__global__ __launch_bounds__(64) void scan_bsum_kernel(
    const int* __restrict__ bsum, int* __restrict__ boff)
{
    const int tid = threadIdx.x;
    int v = (tid < SCAN_NB) ? bsum[tid] : 0;
    int inc = v;
#pragma unroll
    for (int d = 1; d < 64; d <<= 1) {
        int u = __shfl_up(inc, d);
        if (tid >= d) inc += u;
    }
    if (tid < SCAN_NB) boff[tid] = inc - v;   // exclusive prefix
}

// -------- CSR build step 3: block-local scan + write off ------------------
__global__ __launch_bounds__(256) void scan_write_kernel(
    const float* __restrict__ norm, const int* __restrict__ boff,
    int* __restrict__ off)
{
    const int tid = threadIdx.x;
    const int idx = blockIdx.x * 1024 + tid * 4;

    int4 v = make_int4(0, 0, 0, 0);
    if (idx < N_NODES) {
        float4 n = *(const float4*)(norm + idx);
        v.x = deg_from_norm(n.x); v.y = deg_from_norm(n.y);
        v.z = deg_from_norm(n.z); v.w = deg_from_norm(n.w);
    }
    const int s = v.x + v.y + v.z + v.w;

    const int lane = tid & 63, w = tid >> 6;
    int inc = s;
#pragma unroll
    for (int d = 1; d < 64; d <<= 1) {
        int u = __shfl_up(inc, d);
        if (lane >= d) inc += u;
    }
    __shared__ int wsum[4];
    if (lane == 63) wsum[w] = inc;
    __syncthreads();
    int woff = 0;
    for (int i = 0; i < w; ++i) woff += wsum[i];

    int o0 = boff[blockIdx.x] + woff + inc - s;
    int o1 = o0 + v.x;
    int o2 = o1 + v.y;
    int o3 = o2 + v.z;

    if (idx < N_NODES) {
        *(int4*)(off + idx) = make_int4(o0, o1, o2, o3);
    }
}

// -------- Pass 2: bucket -> esrc scatter, LDS cursors ---------------------
// One block per bucket (256 dst nodes). Cursors live in LDS (no global
// atomics); the esrc write window per block is the bucket's contiguous
// ~16 KB segment -> L2-resident, lines fully filled before writeback.
// Final cursors -> cur (aggregate's end pointers; deg-0 phantom guard).
__global__ __launch_bounds__(256) void scatter_kernel(
    const int2* __restrict__ bucketbuf, const int* __restrict__ bcur,
    const int* __restrict__ off, int* __restrict__ cur,
    int* __restrict__ esrc)
{
    const int tid = threadIdx.x;
    const int b = blockIdx.x;
    __shared__ int lcur[256];
    const int g = b * 256 + tid;
    lcur[tid] = (g < N_NODES) ? off[g] : 0;
    __syncthreads();

    const int n = bcur[b];
    const int2* buf = bucketbuf + (size_t)b * BUCKET_CAP;
    for (int i = tid; i < n; i += 256) {
        int2 p = buf[i];
        int pos = atomicAdd(&lcur[p.y & 255], 1);
        esrc[pos] = p.x;
    }
    __syncthreads();
    if (g < N_NODES) cur[g] = lcur[tid];
}

// -------- Kernel D: gather-aggregate (fp16 t) + fused finalize ------------
// 16 lanes per dst node; lane l owns halfs [8l..8l+7] (16 B load per edge).
// End pointer is cur[g] (post-scatter). Edge loop unrolled x2.
__global__ __launch_bounds__(256) void aggregate_kernel(
    const int* __restrict__ off, const int* __restrict__ cur,
    const int* __restrict__ esrc, const _Float16* __restrict__ t,
    const float* __restrict__ norm, const float* __restrict__ b,
    float* __restrict__ out)
{
    const int g = blockIdx.x * 16 + (threadIdx.x >> 4);
    if (g >= N_NODES) return;
    const int l = threadIdx.x & 15;
    const int c = l << 3;
    const int i0 = off[g], i1 = cur[g];

    float acc0[8], acc1[8];
#pragma unroll
    for (int j = 0; j < 8; ++j) { acc0[j] = 0.f; acc1[j] = 0.f; }

    int i = i0;
    for (; i + 2 <= i1; i += 2) {
        int s0 = esrc[i];
        int s1 = esrc[i + 1];
        half8 v0 = *(const half8*)(t + (size_t)s0 * 128 + c);
        half8 v1 = *(const half8*)(t + (size_t)s1 * 128 + c);
#pragma unroll
        for (int j = 0; j < 8; ++j) { acc0[j] += (float)v0[j]; acc1[j] += (float)v1[j]; }
    }
    if (i < i1) {
        int s0 = esrc[i];
        half8 v0 = *(const half8*)(t + (size_t)s0 * 128 + c);
#pragma unroll
        for (int j = 0; j < 8; ++j) acc0[j] += (float)v0[j];
    }

    const float nv = norm[g];
    const float4 b0 = *(const float4*)(b + c);
    const float4 b1 = *(const float4*)(b + c + 4);
    float4 o0 = make_float4((acc0[0] + acc1[0]) * nv + b0.x,
                            (acc0[1] + acc1[1]) * nv + b0.y,
                            (acc0[2] + acc1[2]) * nv + b0.z,
                            (acc0[3] + acc1[3]) * nv + b0.w);
    float4 o1 = make_float4((acc0[4] + acc1[4]) * nv + b1.x,
                            (acc0[5] + acc1[5]) * nv + b1.y,
                            (acc0[6] + acc1[6]) * nv + b1.z,
                            (acc0[7] + acc1[7]) * nv + b1.w);
    *(float4*)(out + (size_t)g * 128 + c) = o0;
    *(float4*)(out + (size_t)g * 128 + c + 4) = o1;
}

static inline size_t align256(size_t x) { return (x + 255) & ~(size_t)255; }

extern "C" void kernel_launch(void* const* d_in, const int* in_sizes, int n_in,
                              void* d_out, int out_size, void* d_ws, size_t ws_size,
                              hipStream_t stream)
{
    const float* h    = (const float*)d_in[0];
    const float* norm = (const float*)d_in[1];
    const float* W    = (const float*)d_in[2];
    const float* b    = (const float*)d_in[3];
    const int*   src  = (const int*)d_in[4];
    const int*   dst  = (const int*)d_in[5];
    float* out = (float*)d_out;

    // workspace layout
    char* ws = (char*)d_ws;
    size_t o = 0;
    _Float16* t = (_Float16*)(ws + o);  o = align256(o + (size_t)N_NODES * 128 * 2);
    int* off = (int*)(ws + o);          o = align256(o + (size_t)N_NODES * 4);
    int* cur = (int*)(ws + o);          o = align256(o + (size_t)N_NODES * 4);
    int* esrc = (int*)(ws + o);         o = align256(o + ((size_t)N_EDGES + 1024) * 4);
    int* bsum = (int*)(ws + o);         o = align256(o + (size_t)SCAN_NB * 4);
    int* boff = (int*)(ws + o);         o = align256(o + (size_t)SCAN_NB * 4);
    int* bcur = (int*)(ws + o);         o = align256(o + (size_t)NBUCKETS * 4);
    int2* bucketbuf = (int2*)(ws + o);  o = align256(o + (size_t)NBUCKETS * BUCKET_CAP * 8);

    scan_sums_kernel<<<SCAN_NB, 256, 0, stream>>>(norm, bsum, bcur);
    scan_bsum_kernel<<<1, 64, 0, stream>>>(bsum, boff);
    scan_write_kernel<<<SCAN_NB, 256, 0, stream>>>(norm, boff, off);
    fused_gemm_bin_kernel<<<FUSED_NB, 256, 0, stream>>>(h, norm, W, t,
                                                        src, dst, bcur, bucketbuf);
    scatter_kernel<<<NBUCKETS, 256, 0, stream>>>(bucketbuf, bcur, off, cur, esrc);
    aggregate_kernel<<<(N_NODES + 15) / 16, 256, 0, stream>>>(off, cur, esrc, t, norm, b, out);
}

// Round 9
// 74.839 us; speedup vs baseline: 1.4072x; 1.4072x over previous
//
#include <hip/hip_runtime.h>

#define N_NODES 50000
#define N_EDGES 800000
#define SCAN_NB 49        // ceil(50000 / 1024) blocks, 1024 elements per block

#define NBUCKETS 196      // ceil(50000/256): bucket = dst >> 8 (256 nodes each)
#define BIN_EDGES 4096    // edges per bin block
#define BIN_NB 196        // ceil(800000/4096)
#define BUCKET_CAP 5120   // slots per bucket (mean 4096, sd ~64 -> 16 sigma margin)

#define GEMM_NB ((N_NODES + 63) / 64)          // 782 gemm tiles (64 rows each)
#define FUSED_NB 980                           // 196*5; bid%5==4 -> bin role

typedef __attribute__((ext_vector_type(4))) _Float16 half4;
typedef __attribute__((ext_vector_type(8))) _Float16 half8;
typedef __attribute__((ext_vector_type(4))) float f32x4;

// Recover in-degree from GCN norm: norm = max(deg,1)^-0.5 (fp32).
// deg=0 reconstructs as 1 (harmless over-allocation; aggregate uses the
// post-scatter cursor as end pointer, so phantom slots are never read).
__device__ __forceinline__ int deg_from_norm(float n)
{
    return __float2int_rn(1.0f / (n * n));
}

// -------- Prep: Wt[c][k] = fp16(W[k][c]) ----------------------------------
// 32 KB fp16 transposed W; stays L2-hot, every GEMM block stages from it.
// Coalesced reads (consecutive threads -> consecutive c), 8B packed writes.
__global__ __launch_bounds__(256) void prep_wt_kernel(
    const float* __restrict__ W, _Float16* __restrict__ Wt)
{
    const int e = blockIdx.x * 256 + threadIdx.x;   // 4096 threads
    const int c = e & 127;
    const int k4 = (e >> 7) << 2;
    half4 v;
    v.x = (_Float16)W[(k4 + 0) * 128 + c];
    v.y = (_Float16)W[(k4 + 1) * 128 + c];
    v.z = (_Float16)W[(k4 + 2) * 128 + c];
    v.w = (_Float16)W[(k4 + 3) * 128 + c];
    *(half4*)(Wt + (size_t)c * 128 + k4) = v;
}

// -------- Fused Kernel A: MFMA gemm_scale tiles + edge binning ------------
// Blocks with bid%5==4 bin 4096 edges into per-bucket sequential streams
// (bucket = dst>>8); the rest compute one 64-row GEMM tile each using
// mfma_f32_16x16x32_f16 (fp16 inputs, fp32 accum). Round-8 postmortem:
// no register pipelining (ILP costs VGPR/occupancy here; TLP hides latency).
// Fragment layout (guide-verified 16x16x32): A/B lane l&15 = row/col,
// k = (l>>4)*8 + j; C/D col = l&15, row = (l>>4)*4 + reg.
// SESSION RULE (rounds 2 & 4): no min-waves clause — it collapses VGPRs and
// spills the accumulators (WRITE_SIZE tripwire 12.5 MB -> 183-564 MB).
__global__ __launch_bounds__(256) void fused_gemm_bin_kernel(
    const float* __restrict__ h, const float* __restrict__ norm,
    const _Float16* __restrict__ Wt, _Float16* __restrict__ t,
    const int* __restrict__ src, const int* __restrict__ dst,
    int* __restrict__ bcur, int2* __restrict__ bucketbuf)
{
    const int tid = threadIdx.x;
    const int bid = blockIdx.x;

    if (bid % 5 == 4) {
        // ---- bin role: 4096 edges -> 196 bucket streams --------------------
        __shared__ int hist[NBUCKETS];
        const int bs = (bid / 5) * BIN_EDGES;
        for (int i = tid; i < NBUCKETS; i += 256) hist[i] = 0;
        __syncthreads();
#pragma unroll
        for (int j = 0; j < 4; ++j) {
            int e4 = bs + (j * 256 + tid) * 4;
            if (e4 < N_EDGES) {               // 4096 & 1280 both %4==0
                int4 d4 = *(const int4*)(dst + e4);
                atomicAdd(&hist[d4.x >> 8], 1);
                atomicAdd(&hist[d4.y >> 8], 1);
                atomicAdd(&hist[d4.z >> 8], 1);
                atomicAdd(&hist[d4.w >> 8], 1);
            }
        }
        __syncthreads();
        int base = 0;
        if (tid < NBUCKETS) {
            int hc = hist[tid];
            if (hc) base = atomicAdd(&bcur[tid], hc);
        }
        __syncthreads();
        if (tid < NBUCKETS) hist[tid] = base;   // reuse as running cursor
        __syncthreads();
#pragma unroll
        for (int j = 0; j < 4; ++j) {
            int e4 = bs + (j * 256 + tid) * 4;
            if (e4 < N_EDGES) {
                int4 d4 = *(const int4*)(dst + e4);
                int4 s4 = *(const int4*)(src + e4);
                int b0, p;
                b0 = d4.x >> 8; p = atomicAdd(&hist[b0], 1);
                bucketbuf[(size_t)b0 * BUCKET_CAP + p] = make_int2(s4.x, d4.x);
                b0 = d4.y >> 8; p = atomicAdd(&hist[b0], 1);
                bucketbuf[(size_t)b0 * BUCKET_CAP + p] = make_int2(s4.y, d4.y);
                b0 = d4.z >> 8; p = atomicAdd(&hist[b0], 1);
                bucketbuf[(size_t)b0 * BUCKET_CAP + p] = make_int2(s4.z, d4.z);
                b0 = d4.w >> 8; p = atomicAdd(&hist[b0], 1);
                bucketbuf[(size_t)b0 * BUCKET_CAP + p] = make_int2(s4.w, d4.w);
            }
        }
        return;
    }

    // ---- gemm role: one 64-row tile, 4 waves x 16 rows, MFMA ---------------
    __shared__ __align__(16) _Float16 WtS[128 * 136];  // [c][k] pad 136, 34.8 KB
    __shared__ __align__(16) _Float16 HhS[64 * 136];   // [r][k] pad 136, 17.4 KB
    __shared__ float norms[64];
    const int gemm_id = bid - bid / 5;
    if (gemm_id >= GEMM_NB) return;
    const int rbase = gemm_id * 64;

    // stage Wt (32 KB, L2-hot): 8 x 16B per thread, coalesced
#pragma unroll
    for (int i = 0; i < 8; ++i) {
        int f = i * 256 + tid;            // 0..2047
        int c = f >> 4;                   // 0..127
        int k8 = (f & 15) << 3;           // 0..120
        *(half8*)(WtS + c * 136 + k8) = *(const half8*)(Wt + (size_t)c * 128 + k8);
    }
    // stage h tile -> fp16: 8 x float4 per thread, coalesced
#pragma unroll
    for (int i = 0; i < 8; ++i) {
        int f = i * 256 + tid;            // 0..2047
        int row = f >> 5;                 // 0..63
        int c4 = (f & 31) << 2;           // 0..124
        int gr = rbase + row;
        float4 v = make_float4(0.f, 0.f, 0.f, 0.f);
        if (gr < N_NODES) v = *(const float4*)(h + (size_t)gr * 128 + c4);
        half4 hv;
        hv.x = (_Float16)v.x; hv.y = (_Float16)v.y;
        hv.z = (_Float16)v.z; hv.w = (_Float16)v.w;
        *(half4*)(HhS + row * 136 + c4) = hv;
    }
    if (tid < 64) {
        int gr = rbase + tid;
        norms[tid] = (gr < N_NODES) ? norm[gr] : 0.f;
    }
    __syncthreads();

    const int wid = tid >> 6, lane = tid & 63;
    const int lrow = lane & 15;           // A row / B col within 16-tile
    const int lk = (lane >> 4) << 3;      // k octet
    const int r0 = wid * 16;

    // A fragments: h rows, all 4 K-steps (16 VGPR)
    half8 a[4];
#pragma unroll
    for (int ks = 0; ks < 4; ++ks)
        a[ks] = *(const half8*)(HhS + (r0 + lrow) * 136 + ks * 32 + lk);

    // per-lane output rows (fixed across col-tiles) + their norms
    const int rq = r0 + ((lane >> 4) << 2);
    float nv[4];
#pragma unroll
    for (int reg = 0; reg < 4; ++reg) nv[reg] = norms[rq + reg];

#pragma unroll
    for (int ct = 0; ct < 8; ++ct) {
        const int c0 = ct * 16;
        f32x4 acc = {0.f, 0.f, 0.f, 0.f};
#pragma unroll
        for (int ks = 0; ks < 4; ++ks) {
            half8 bf = *(const half8*)(WtS + (c0 + lrow) * 136 + ks * 32 + lk);
            acc = __builtin_amdgcn_mfma_f32_16x16x32_f16(a[ks], bf, acc, 0, 0, 0);
        }
#pragma unroll
        for (int reg = 0; reg < 4; ++reg) {
            int gr = rbase + rq + reg;
            if (gr < N_NODES)
                t[(size_t)gr * 128 + c0 + lrow] = (_Float16)(acc[reg] * nv[reg]);
        }
    }
}

// -------- CSR build step 1: per-block degree sums (from norm) -------------
// Block 0 also zeroes the 196 bucket cursors for the binning pass.
__global__ __launch_bounds__(256) void scan_sums_kernel(
    const float* __restrict__ norm, int* __restrict__ bsum,
    int* __restrict__ bcur)
{
    const int tid = threadIdx.x;
    if (blockIdx.x == 0 && tid < NBUCKETS) bcur[tid] = 0;
    const int idx = blockIdx.x * 1024 + tid * 4;
    int s = 0;
    if (idx < N_NODES) {                 // 50000 % 4 == 0: group fully in-range
        float4 n = *(const float4*)(norm + idx);
        s = deg_from_norm(n.x) + deg_from_norm(n.y) +
            deg_from_norm(n.z) + deg_from_norm(n.w);
    }
#pragma unroll
    for (int d = 32; d > 0; d >>= 1) s += __shfl_down(s, d);
    __shared__ int ws[4];
    if ((tid & 63) == 0) ws[tid >> 6] = s;
    __syncthreads();
    if (tid == 0) bsum[blockIdx.x] = ws[0] + ws[1] + ws[2] + ws[3];
}

// -------- CSR build step 2: exclusive scan of 49 block sums (1 wave) ------
__global__ __launch_bounds__(64) void scan_bsum_kernel(
    const int* __restrict__ bsum, int* __restrict__ boff)
{
    const int tid = threadIdx.x;
    int v = (tid < SCAN_NB) ? bsum[tid] : 0;
    int inc = v;
#pragma unroll
    for (int d = 1; d < 64; d <<= 1) {
        int u = __shfl_up(inc, d);
        if (tid >= d) inc += u;
    }
    if (tid < SCAN_NB) boff[tid] = inc - v;   // exclusive prefix
}

// -------- CSR build step 3: block-local scan + write off ------------------
__global__ __launch_bounds__(256) void scan_write_kernel(
    const float* __restrict__ norm, const int* __restrict__ boff,
    int* __restrict__ off)
{
    const int tid = threadIdx.x;
    const int idx = blockIdx.x * 1024 + tid * 4;

    int4 v = make_int4(0, 0, 0, 0);
    if (idx < N_NODES) {
        float4 n = *(const float4*)(norm + idx);
        v.x = deg_from_norm(n.x); v.y = deg_from_norm(n.y);
        v.z = deg_from_norm(n.z); v.w = deg_from_norm(n.w);
    }
    const int s = v.x + v.y + v.z + v.w;

    const int lane = tid & 63, w = tid >> 6;
    int inc = s;
#pragma unroll
    for (int d = 1; d < 64; d <<= 1) {
        int u = __shfl_up(inc, d);
        if (lane >= d) inc += u;
    }
    __shared__ int wsum[4];
    if (lane == 63) wsum[w] = inc;
    __syncthreads();
    int woff = 0;
    for (int i = 0; i < w; ++i) woff += wsum[i];

    int o0 = boff[blockIdx.x] + woff + inc - s;
    int o1 = o0 + v.x;
    int o2 = o1 + v.y;
    int o3 = o2 + v.z;

    if (idx < N_NODES) {
        *(int4*)(off + idx) = make_int4(o0, o1, o2, o3);
    }
}

// -------- Pass 2: bucket -> esrc scatter, LDS cursors ---------------------
// One block per bucket (256 dst nodes). Cursors live in LDS (no global
// atomics); the esrc write window per block is the bucket's contiguous
// ~16 KB segment -> L2-resident, lines fully filled before writeback.
// Final cursors -> cur (aggregate's end pointers; deg-0 phantom guard).
__global__ __launch_bounds__(256) void scatter_kernel(
    const int2* __restrict__ bucketbuf, const int* __restrict__ bcur,
    const int* __restrict__ off, int* __restrict__ cur,
    int* __restrict__ esrc)
{
    const int tid = threadIdx.x;
    const int b = blockIdx.x;
    __shared__ int lcur[256];
    const int g = b * 256 + tid;
    lcur[tid] = (g < N_NODES) ? off[g] : 0;
    __syncthreads();

    const int n = bcur[b];
    const int2* buf = bucketbuf + (size_t)b * BUCKET_CAP;
    for (int i = tid; i < n; i += 256) {
        int2 p = buf[i];
        int pos = atomicAdd(&lcur[p.y & 255], 1);
        esrc[pos] = p.x;
    }
    __syncthreads();
    if (g < N_NODES) cur[g] = lcur[tid];
}

// -------- Kernel D: gather-aggregate (fp16 t) + fused finalize ------------
// 16 lanes per dst node; lane l owns halfs [8l..8l+7] (16 B load per edge).
// End pointer is cur[g] (post-scatter). Edge loop unrolled x2.
__global__ __launch_bounds__(256) void aggregate_kernel(
    const int* __restrict__ off, const int* __restrict__ cur,
    const int* __restrict__ esrc, const _Float16* __restrict__ t,
    const float* __restrict__ norm, const float* __restrict__ b,
    float* __restrict__ out)
{
    const int g = blockIdx.x * 16 + (threadIdx.x >> 4);
    if (g >= N_NODES) return;
    const int l = threadIdx.x & 15;
    const int c = l << 3;
    const int i0 = off[g], i1 = cur[g];

    float acc0[8], acc1[8];
#pragma unroll
    for (int j = 0; j < 8; ++j) { acc0[j] = 0.f; acc1[j] = 0.f; }

    int i = i0;
    for (; i + 2 <= i1; i += 2) {
        int s0 = esrc[i];
        int s1 = esrc[i + 1];
        half8 v0 = *(const half8*)(t + (size_t)s0 * 128 + c);
        half8 v1 = *(const half8*)(t + (size_t)s1 * 128 + c);
#pragma unroll
        for (int j = 0; j < 8; ++j) { acc0[j] += (float)v0[j]; acc1[j] += (float)v1[j]; }
    }
    if (i < i1) {
        int s0 = esrc[i];
        half8 v0 = *(const half8*)(t + (size_t)s0 * 128 + c);
#pragma unroll
        for (int j = 0; j < 8; ++j) acc0[j] += (float)v0[j];
    }

    const float nv = norm[g];
    const float4 b0 = *(const float4*)(b + c);
    const float4 b1 = *(const float4*)(b + c + 4);
    float4 o0 = make_float4((acc0[0] + acc1[0]) * nv + b0.x,
                            (acc0[1] + acc1[1]) * nv + b0.y,
                            (acc0[2] + acc1[2]) * nv + b0.z,
                            (acc0[3] + acc1[3]) * nv + b0.w);
    float4 o1 = make_float4((acc0[4] + acc1[4]) * nv + b1.x,
                            (acc0[5] + acc1[5]) * nv + b1.y,
                            (acc0[6] + acc1[6]) * nv + b1.z,
                            (acc0[7] + acc1[7]) * nv + b1.w);
    *(float4*)(out + (size_t)g * 128 + c) = o0;
    *(float4*)(out + (size_t)g * 128 + c + 4) = o1;
}

static inline size_t align256(size_t x) { return (x + 255) & ~(size_t)255; }

extern "C" void kernel_launch(void* const* d_in, const int* in_sizes, int n_in,
                              void* d_out, int out_size, void* d_ws, size_t ws_size,
                              hipStream_t stream)
{
    const float* h    = (const float*)d_in[0];
    const float* norm = (const float*)d_in[1];
    const float* W    = (const float*)d_in[2];
    const float* b    = (const float*)d_in[3];
    const int*   src  = (const int*)d_in[4];
    const int*   dst  = (const int*)d_in[5];
    float* out = (float*)d_out;

    // workspace layout
    char* ws = (char*)d_ws;
    size_t o = 0;
    _Float16* t = (_Float16*)(ws + o);  o = align256(o + (size_t)N_NODES * 128 * 2);
    _Float16* Wt = (_Float16*)(ws + o); o = align256(o + (size_t)128 * 128 * 2);
    int* off = (int*)(ws + o);          o = align256(o + (size_t)N_NODES * 4);
    int* cur = (int*)(ws + o);          o = align256(o + (size_t)N_NODES * 4);
    int* esrc = (int*)(ws + o);         o = align256(o + ((size_t)N_EDGES + 1024) * 4);
    int* bsum = (int*)(ws + o);         o = align256(o + (size_t)SCAN_NB * 4);
    int* boff = (int*)(ws + o);         o = align256(o + (size_t)SCAN_NB * 4);
    int* bcur = (int*)(ws + o);         o = align256(o + (size_t)NBUCKETS * 4);
    int2* bucketbuf = (int2*)(ws + o);  o = align256(o + (size_t)NBUCKETS * BUCKET_CAP * 8);

    prep_wt_kernel<<<16, 256, 0, stream>>>(W, Wt);
    scan_sums_kernel<<<SCAN_NB, 256, 0, stream>>>(norm, bsum, bcur);
    scan_bsum_kernel<<<1, 64, 0, stream>>>(bsum, boff);
    scan_write_kernel<<<SCAN_NB, 256, 0, stream>>>(norm, boff, off);
    fused_gemm_bin_kernel<<<FUSED_NB, 256, 0, stream>>>(h, norm, Wt, t,
                                                        src, dst, bcur, bucketbuf);
    scatter_kernel<<<NBUCKETS, 256, 0, stream>>>(bucketbuf, bcur, off, cur, esrc);
    aggregate_kernel<<<(N_NODES + 15) / 16, 256, 0, stream>>>(off, cur, esrc, t, norm, b, out);
}